// Round 1
// baseline (606.433 us; speedup 1.0000x reference)
//
#include <hip/hip_runtime.h>
#include <hip/hip_bf16.h>
#include <cstdint>

typedef __attribute__((ext_vector_type(8))) short short8;   // 8 bf16 = 4 VGPRs
typedef __attribute__((ext_vector_type(4))) float floatx4;  // MFMA C/D

__device__ __forceinline__ unsigned short f32_to_bf16_rne(float f) {
  uint32_t u = __float_as_uint(f);
  u += 0x7FFFu + ((u >> 16) & 1u);   // round-to-nearest-even (inputs are finite normals)
  return (unsigned short)(u >> 16);
}

// x fp32 -> bf16 bits, 4 elems/thread
__global__ void cvt_x_kernel(const float4* __restrict__ x, ushort4* __restrict__ o, int n4) {
  int i = blockIdx.x * blockDim.x + threadIdx.x;
  if (i >= n4) return;
  float4 v = x[i];
  ushort4 r;
  r.x = f32_to_bf16_rne(v.x);
  r.y = f32_to_bf16_rne(v.y);
  r.z = f32_to_bf16_rne(v.z);
  r.w = f32_to_bf16_rne(v.w);
  o[i] = r;
}

// w int32 in [-128,127] -> bf16 bits (exact: <=8 significand bits)
__global__ void cvt_w_kernel(const int4* __restrict__ w, ushort4* __restrict__ o, int n4) {
  int i = blockIdx.x * blockDim.x + threadIdx.x;
  if (i >= n4) return;
  int4 v = w[i];
  ushort4 r;
  r.x = (unsigned short)(__float_as_uint((float)v.x) >> 16);
  r.y = (unsigned short)(__float_as_uint((float)v.y) >> 16);
  r.z = (unsigned short)(__float_as_uint((float)v.z) >> 16);
  r.w = (unsigned short)(__float_as_uint((float)v.w) >> 16);
  o[i] = r;
}

__device__ __forceinline__ void async16(const void* g, void* l) {
  // global -> LDS direct copy, 16 B/lane; LDS dest is wave-uniform base + lane*16
  __builtin_amdgcn_global_load_lds((__attribute__((address_space(1))) void*)(g),
                                   (__attribute__((address_space(3))) void*)(l), 16, 0, 0);
}

// C[m,n] = scale[n] * sum_k A[m,k]*B[n,k] + bias[n]
// A: [M,K] bf16 bits, B: [N,K] bf16 bits (B^T layout), C: [M,N] fp32
__global__ __launch_bounds__(256) void gemm_bt_bf16(
    const unsigned short* __restrict__ A, const unsigned short* __restrict__ B,
    const float* __restrict__ scale, const float* __restrict__ bias,
    float* __restrict__ C, int M, int N, int K) {
  constexpr int BM = 128, BN = 128, BK = 32;
  __shared__ unsigned short sA[BM * BK];  // 8 KB, row-major [128][32], no pad (global_load_lds)
  __shared__ unsigned short sB[BN * BK];  // 8 KB

  const int tid  = threadIdx.x;
  const int lane = tid & 63;
  const int wv   = tid >> 6;        // 4 waves
  const int wm   = wv >> 1;         // 2x2 wave grid -> each wave owns 64x64
  const int wn   = wv & 1;
  const int aM   = blockIdx.y * BM;
  const int bN   = blockIdx.x * BN;

  // --- staging: 128 rows x 4 segs(16B) = 512 lane-tasks; 256 threads -> 2 issues each per matrix
  const int t0 = tid, t1 = tid + 256;
  const unsigned short* gA0 = A + (size_t)(aM + (t0 >> 2)) * K + (t0 & 3) * 8;
  const unsigned short* gA1 = A + (size_t)(aM + (t1 >> 2)) * K + (t1 & 3) * 8;
  const unsigned short* gB0 = B + (size_t)(bN + (t0 >> 2)) * K + (t0 & 3) * 8;
  const unsigned short* gB1 = B + (size_t)(bN + (t1 >> 2)) * K + (t1 & 3) * 8;
  unsigned short* lA0 = sA + t0 * 8;  // byte offset tid*16: contiguous in lane order per wave
  unsigned short* lA1 = sA + t1 * 8;
  unsigned short* lB0 = sB + t0 * 8;
  unsigned short* lB1 = sB + t1 * 8;

  // --- LDS->frag read offsets: A[m=lane&15][k=quad*8+j] (m120-verified A-operand layout)
  const int row  = lane & 15;
  const int quad = lane >> 4;
  const unsigned short* rA = sA + (size_t)(wm * 64 + row) * BK + quad * 8;
  const unsigned short* rB = sB + (size_t)(wn * 64 + row) * BK + quad * 8;

  floatx4 acc[4][4] = {};

  for (int k0 = 0; k0 < K; k0 += BK) {
    __syncthreads();  // previous iter's LDS reads done before overwrite
    async16(gA0, lA0);
    async16(gA1, lA1);
    async16(gB0, lB0);
    async16(gB1, lB1);
    gA0 += BK; gA1 += BK; gB0 += BK; gB1 += BK;
    __syncthreads();  // drains vmcnt(0): staged tiles visible

    short8 af[4], bf[4];
#pragma unroll
    for (int t = 0; t < 4; ++t) {
      af[t] = *(const short8*)(rA + t * 16 * BK);
      bf[t] = *(const short8*)(rB + t * 16 * BK);
    }
#pragma unroll
    for (int i = 0; i < 4; ++i)
#pragma unroll
      for (int j = 0; j < 4; ++j)
        acc[i][j] = __builtin_amdgcn_mfma_f32_16x16x32_bf16(af[i], bf[j], acc[i][j], 0, 0, 0);
  }

  // --- epilogue: C/D layout col=lane&15, row=(lane>>4)*4+reg (m89-verified)
#pragma unroll
  for (int j = 0; j < 4; ++j) {
    const int n = bN + wn * 64 + j * 16 + row;
    const float s = scale[n];
    const float b = bias[n];
#pragma unroll
    for (int i = 0; i < 4; ++i) {
      const int m0 = aM + wm * 64 + i * 16 + quad * 4;
      floatx4 c = acc[i][j];
      C[(size_t)(m0 + 0) * N + n] = c[0] * s + b;
      C[(size_t)(m0 + 1) * N + n] = c[1] * s + b;
      C[(size_t)(m0 + 2) * N + n] = c[2] * s + b;
      C[(size_t)(m0 + 3) * N + n] = c[3] * s + b;
    }
  }
}

// Insurance only: used if ws_size is too small for the bf16 staging buffers.
__global__ void naive_kernel(const float* __restrict__ x, const int* __restrict__ w,
                             const float* __restrict__ s, const float* __restrict__ b,
                             float* __restrict__ y, int M, int N, int K) {
  int n = blockIdx.x * blockDim.x + threadIdx.x;
  int m = blockIdx.y;
  if (n >= N) return;
  float acc = 0.f;
  for (int k = 0; k < K; ++k) acc += x[(size_t)m * K + k] * (float)w[(size_t)n * K + k];
  y[(size_t)m * N + n] = acc * s[n] + b[n];
}

extern "C" void kernel_launch(void* const* d_in, const int* in_sizes, int n_in,
                              void* d_out, int out_size, void* d_ws, size_t ws_size,
                              hipStream_t stream) {
  const float* x     = (const float*)d_in[0];
  const int*   wq    = (const int*)d_in[1];
  const float* scale = (const float*)d_in[2];
  const float* bias  = (const float*)d_in[3];
  float* y = (float*)d_out;

  const int xN = in_sizes[0];           // M*K
  const int wN = in_sizes[1];           // N*K
  const int N  = in_sizes[2];           // D_OUT
  const int K  = wN / N;
  const int M  = xN / K;

  const size_t need = (size_t)xN * 2 + (size_t)wN * 2;  // 96 MiB here
  if (ws_size >= need && (M % 128) == 0 && (N % 128) == 0 && (K % 32) == 0 &&
      (xN % 4) == 0 && (wN % 4) == 0) {
    unsigned short* xb = (unsigned short*)d_ws;
    unsigned short* wb = xb + (size_t)xN;
    cvt_x_kernel<<<(xN / 4 + 255) / 256, 256, 0, stream>>>((const float4*)x, (ushort4*)xb, xN / 4);
    cvt_w_kernel<<<(wN / 4 + 255) / 256, 256, 0, stream>>>((const int4*)wq, (ushort4*)wb, wN / 4);
    dim3 grid(N / 128, M / 128);
    gemm_bt_bf16<<<grid, 256, 0, stream>>>(xb, wb, scale, bias, y, M, N, K);
  } else {
    dim3 grid((N + 255) / 256, M);
    naive_kernel<<<grid, 256, 0, stream>>>(x, wq, scale, bias, y, M, N, K);
  }
}

// Round 2
// 600.366 us; speedup vs baseline: 1.0101x; 1.0101x over previous
//
#include <hip/hip_runtime.h>
#include <hip/hip_bf16.h>
#include <cstdint>

typedef __attribute__((ext_vector_type(8))) short short8;            // 8 bf16 = 4 VGPRs
typedef __attribute__((ext_vector_type(4))) float floatx4;           // MFMA C/D
typedef __attribute__((ext_vector_type(8))) unsigned short ushort8v; // 16B store

__device__ __forceinline__ unsigned short f32_to_bf16_rne(float f) {
  uint32_t u = __float_as_uint(f);
  u += 0x7FFFu + ((u >> 16) & 1u);   // round-to-nearest-even (inputs are finite normals)
  return (unsigned short)(u >> 16);
}

// x fp32 -> bf16 bits, 8 elems/thread, 16B stores
__global__ void cvt_x_kernel(const float4* __restrict__ x, ushort8v* __restrict__ o, int n8) {
  int i = blockIdx.x * blockDim.x + threadIdx.x;
  if (i >= n8) return;
  float4 a = x[i * 2], b = x[i * 2 + 1];
  ushort8v r;
  r[0] = f32_to_bf16_rne(a.x); r[1] = f32_to_bf16_rne(a.y);
  r[2] = f32_to_bf16_rne(a.z); r[3] = f32_to_bf16_rne(a.w);
  r[4] = f32_to_bf16_rne(b.x); r[5] = f32_to_bf16_rne(b.y);
  r[6] = f32_to_bf16_rne(b.z); r[7] = f32_to_bf16_rne(b.w);
  o[i] = r;
}

// w int32 in [-128,127] -> bf16 bits (exact: <=8 significand bits), 8 elems/thread
__global__ void cvt_w_kernel(const int4* __restrict__ w, ushort8v* __restrict__ o, int n8) {
  int i = blockIdx.x * blockDim.x + threadIdx.x;
  if (i >= n8) return;
  int4 a = w[i * 2], b = w[i * 2 + 1];
  ushort8v r;
  r[0] = (unsigned short)(__float_as_uint((float)a.x) >> 16);
  r[1] = (unsigned short)(__float_as_uint((float)a.y) >> 16);
  r[2] = (unsigned short)(__float_as_uint((float)a.z) >> 16);
  r[3] = (unsigned short)(__float_as_uint((float)a.w) >> 16);
  r[4] = (unsigned short)(__float_as_uint((float)b.x) >> 16);
  r[5] = (unsigned short)(__float_as_uint((float)b.y) >> 16);
  r[6] = (unsigned short)(__float_as_uint((float)b.z) >> 16);
  r[7] = (unsigned short)(__float_as_uint((float)b.w) >> 16);
  o[i] = r;
}

__device__ __forceinline__ void async16(const void* g, void* l) {
  // global -> LDS direct copy, 16 B/lane; LDS dest is wave-uniform base + lane*16
  __builtin_amdgcn_global_load_lds((__attribute__((address_space(1))) void*)(g),
                                   (__attribute__((address_space(3))) void*)(l), 16, 0, 0);
}

// C[m,n] = scale[n] * sum_k A[m,k]*B[n,k] + bias[n]
// A: [M,K] bf16 bits, B: [N,K] bf16 bits (B^T layout), C: [M,N] fp32
// LDS layout: physical seg = logical seg XOR ((row>>1)&3) — spreads ds_read_b128
// quarter-phases across all 8 bank-quads (2-way = free, m136) while keeping the
// global_load_lds destination tid-contiguous (wave-uniform-base constraint).
__global__ __launch_bounds__(256) void gemm_bt_bf16(
    const unsigned short* __restrict__ A, const unsigned short* __restrict__ B,
    const float* __restrict__ scale, const float* __restrict__ bias,
    float* __restrict__ C, int M, int N, int K) {
  constexpr int BM = 128, BN = 128, BK = 32;
  __shared__ unsigned short sA[BM * BK];  // 8 KB
  __shared__ unsigned short sB[BN * BK];  // 8 KB

  const int tid  = threadIdx.x;
  const int lane = tid & 63;
  const int wv   = tid >> 6;        // 4 waves
  const int wm   = wv >> 1;         // 2x2 wave grid -> each wave owns 64x64
  const int wn   = wv & 1;
  const int aM   = blockIdx.y * BM;
  const int bN   = blockIdx.x * BN;

  // --- staging: 128 rows x 4 segs(16B) = 512 lane-tasks; 256 threads -> 2 issues each
  // physical slot t holds logical (row = t>>2, seg = (t&3) ^ ((row>>1)&3))
  const int t0 = tid, t1 = tid + 256;
  const int r0 = t0 >> 2, s0 = (t0 & 3) ^ ((r0 >> 1) & 3);
  const int r1 = t1 >> 2, s1 = (t1 & 3) ^ ((r1 >> 1) & 3);
  const unsigned short* gA0 = A + (size_t)(aM + r0) * K + s0 * 8;
  const unsigned short* gA1 = A + (size_t)(aM + r1) * K + s1 * 8;
  const unsigned short* gB0 = B + (size_t)(bN + r0) * K + s0 * 8;
  const unsigned short* gB1 = B + (size_t)(bN + r1) * K + s1 * 8;
  unsigned short* lA0 = sA + t0 * 8;
  unsigned short* lA1 = sA + t1 * 8;
  unsigned short* lB0 = sB + t0 * 8;
  unsigned short* lB1 = sB + t1 * 8;

  // --- LDS->frag reads: A[m=lane&15][k=quad*8+j] logical; apply same XOR swizzle.
  // swizzle bits depend only on row&15 (tile-row base is a multiple of 16).
  const int row  = lane & 15;
  const int quad = lane >> 4;
  const int sw   = (row >> 1) & 3;
  const unsigned short* rA = sA + (size_t)(wm * 64 + row) * BK + (quad ^ sw) * 8;
  const unsigned short* rB = sB + (size_t)(wn * 64 + row) * BK + (quad ^ sw) * 8;

  floatx4 acc[4][4] = {};

  for (int k0 = 0; k0 < K; k0 += BK) {
    __syncthreads();  // previous iter's LDS reads done before overwrite
    async16(gA0, lA0);
    async16(gA1, lA1);
    async16(gB0, lB0);
    async16(gB1, lB1);
    gA0 += BK; gA1 += BK; gB0 += BK; gB1 += BK;
    __syncthreads();  // drains vmcnt(0): staged tiles visible

    short8 af[4], bf[4];
#pragma unroll
    for (int t = 0; t < 4; ++t) {
      af[t] = *(const short8*)(rA + t * 16 * BK);
      bf[t] = *(const short8*)(rB + t * 16 * BK);
    }
#pragma unroll
    for (int i = 0; i < 4; ++i)
#pragma unroll
      for (int j = 0; j < 4; ++j)
        acc[i][j] = __builtin_amdgcn_mfma_f32_16x16x32_bf16(af[i], bf[j], acc[i][j], 0, 0, 0);
  }

  // --- epilogue: C/D layout col=lane&15, row=(lane>>4)*4+reg (m89-verified)
#pragma unroll
  for (int j = 0; j < 4; ++j) {
    const int n = bN + wn * 64 + j * 16 + row;
    const float s = scale[n];
    const float b = bias[n];
#pragma unroll
    for (int i = 0; i < 4; ++i) {
      const int m0 = aM + wm * 64 + i * 16 + quad * 4;
      floatx4 c = acc[i][j];
      C[(size_t)(m0 + 0) * N + n] = c[0] * s + b;
      C[(size_t)(m0 + 1) * N + n] = c[1] * s + b;
      C[(size_t)(m0 + 2) * N + n] = c[2] * s + b;
      C[(size_t)(m0 + 3) * N + n] = c[3] * s + b;
    }
  }
}

// Insurance only: used if ws_size is too small for the bf16 staging buffers.
__global__ void naive_kernel(const float* __restrict__ x, const int* __restrict__ w,
                             const float* __restrict__ s, const float* __restrict__ b,
                             float* __restrict__ y, int M, int N, int K) {
  int n = blockIdx.x * blockDim.x + threadIdx.x;
  int m = blockIdx.y;
  if (n >= N) return;
  float acc = 0.f;
  for (int k = 0; k < K; ++k) acc += x[(size_t)m * K + k] * (float)w[(size_t)n * K + k];
  y[(size_t)m * N + n] = acc * s[n] + b[n];
}

extern "C" void kernel_launch(void* const* d_in, const int* in_sizes, int n_in,
                              void* d_out, int out_size, void* d_ws, size_t ws_size,
                              hipStream_t stream) {
  const float* x     = (const float*)d_in[0];
  const int*   wq    = (const int*)d_in[1];
  const float* scale = (const float*)d_in[2];
  const float* bias  = (const float*)d_in[3];
  float* y = (float*)d_out;

  const int xN = in_sizes[0];           // M*K
  const int wN = in_sizes[1];           // N*K
  const int N  = in_sizes[2];           // D_OUT
  const int K  = wN / N;
  const int M  = xN / K;

  const size_t need = (size_t)xN * 2 + (size_t)wN * 2;  // 96 MiB here
  if (ws_size >= need && (M % 128) == 0 && (N % 128) == 0 && (K % 32) == 0 &&
      (xN % 8) == 0 && (wN % 8) == 0) {
    unsigned short* xb = (unsigned short*)d_ws;
    unsigned short* wb = xb + (size_t)xN;
    cvt_x_kernel<<<(xN / 8 + 255) / 256, 256, 0, stream>>>((const float4*)x, (ushort8v*)xb, xN / 8);
    cvt_w_kernel<<<(wN / 8 + 255) / 256, 256, 0, stream>>>((const int4*)wq, (ushort8v*)wb, wN / 8);
    dim3 grid(N / 128, M / 128);
    gemm_bt_bf16<<<grid, 256, 0, stream>>>(xb, wb, scale, bias, y, M, N, K);
  } else {
    dim3 grid((N + 255) / 256, M);
    naive_kernel<<<grid, 256, 0, stream>>>(x, wq, scale, bias, y, M, N, K);
  }
}